// Round 1
// baseline (1132.970 us; speedup 1.0000x reference)
//
#include <hip/hip_runtime.h>
#include <stdint.h>

#define HEADS 6
#define NN 2048
#define BB 4
#define MTOT (BB*NN)   // 8192 rows
#define DEPTH 4

typedef unsigned short u16;
typedef __attribute__((ext_vector_type(8))) short bf16x8;
typedef __attribute__((ext_vector_type(4))) float f32x4;

#define MFMA16(a,b,c) __builtin_amdgcn_mfma_f32_16x16x32_bf16((a),(b),(c),0,0,0)

__device__ __forceinline__ u16 f2bf(float f) {
  union { float f; uint32_t u; } v; v.f = f;
  uint32_t r = v.u + 0x7fffu + ((v.u >> 16) & 1u);
  return (u16)(r >> 16);
}

__device__ __forceinline__ void gload_lds16(const void* g, void* l) {
  __builtin_amdgcn_global_load_lds((const __attribute__((address_space(1))) void*)g,
                                   (__attribute__((address_space(3))) void*)l, 16, 0, 0);
}

// ---------------- weight transpose+convert: in[K][N] f32 -> out[N][K] bf16 ----
__global__ __launch_bounds__(256)
void wtrans_k(const float* __restrict__ in, u16* __restrict__ out, int K, int N) {
  __shared__ float t[32][33];
  const int z = blockIdx.z;
  in  += (size_t)z * K * N;
  out += (size_t)z * K * N;
  const int n0 = blockIdx.x * 32, k0 = blockIdx.y * 32;
  const int tx = threadIdx.x & 31, ty = threadIdx.x >> 5;   // 32 x 8
#pragma unroll
  for (int i = 0; i < 4; ++i)
    t[ty + i*8][tx] = in[(size_t)(k0 + ty + i*8) * N + n0 + tx];
  __syncthreads();
#pragma unroll
  for (int i = 0; i < 4; ++i)
    out[(size_t)(n0 + ty + i*8) * K + k0 + tx] = f2bf(t[tx][ty + i*8]);
}

// ---------------- x f32 -> bf16 --------------------------------------------
__global__ __launch_bounds__(256)
void xprep_k(const float* __restrict__ x, u16* __restrict__ xbf, int n) {
  int i = blockIdx.x * 256 + threadIdx.x;
  if (i < n) xbf[i] = f2bf(x[i]);
}

// ---------------- GEMM: C[M,N] = A[M,K](bf16) @ Bt[N,K]^T(bf16) -------------
// MODE 0: QKV split -> qb/kb (row-major per head) + vtb (transposed per head)
// MODE 1: += residual -> outF(f32) + outB(bf16)
// MODE 2: +bias, GELU -> outB(bf16)
// MODE 3: +bias +residual -> outF(f32) + outB(bf16)
template<int MODE>
__global__ __launch_bounds__(256)
void gemm_k(const u16* __restrict__ A, const u16* __restrict__ Bt,
            const float* __restrict__ bias, const float* __restrict__ res,
            float* __restrict__ outF, u16* __restrict__ outB,
            u16* __restrict__ qb, u16* __restrict__ kb, u16* __restrict__ vtb,
            int M, int N, int K) {
  __shared__ u16 smA[128 * 64];
  __shared__ u16 smB[128 * 64];
  const int tid = threadIdx.x;
  const int lane = tid & 63, wv = tid >> 6;
  const int wr = wv >> 1, wc = wv & 1;
  const int row0 = blockIdx.y * 128, col0 = blockIdx.x * 128;
  const int lrow = lane & 15, g = lane >> 4;

  f32x4 acc[4][4];
#pragma unroll
  for (int i = 0; i < 4; ++i)
#pragma unroll
    for (int j = 0; j < 4; ++j) acc[i][j] = f32x4{0.f, 0.f, 0.f, 0.f};

  const int ksteps = K >> 6;
  for (int kt = 0; kt < ksteps; ++kt) {
    const int k0 = kt << 6;
    const u16* Ab = A  + (size_t)row0 * K + k0;
    const u16* Bb = Bt + (size_t)col0 * K + k0;
    // stage 128x64 tiles; LDS linear dest, XOR-swizzled global source (rule #21)
#pragma unroll
    for (int r = 0; r < 4; ++r) {
      int c  = (r * 4 + wv) * 64 + lane;           // chunk 0..1023 (16B each)
      int rw = c >> 3;                              // tile row 0..127
      int kk = ((c & 7) ^ (rw & 7)) * 8;            // swizzled k-slot
      gload_lds16(Ab + (size_t)rw * K + kk, smA + (r * 4 + wv) * 512);
      gload_lds16(Bb + (size_t)rw * K + kk, smB + (r * 4 + wv) * 512);
    }
    __syncthreads();   // drains vmcnt -> LDS valid
#pragma unroll
    for (int kc = 0; kc < 2; ++kc) {
      bf16x8 a[4], b[4];
#pragma unroll
      for (int mi = 0; mi < 4; ++mi) {
        int r = wr * 64 + mi * 16 + lrow;
        int slot = (kc * 4 + g) ^ (r & 7);
        a[mi] = *(const bf16x8*)(smA + r * 64 + slot * 8);
      }
#pragma unroll
      for (int ni = 0; ni < 4; ++ni) {
        int r = wc * 64 + ni * 16 + lrow;
        int slot = (kc * 4 + g) ^ (r & 7);
        b[ni] = *(const bf16x8*)(smB + r * 64 + slot * 8);
      }
#pragma unroll
      for (int mi = 0; mi < 4; ++mi)
#pragma unroll
        for (int ni = 0; ni < 4; ++ni)
          acc[mi][ni] = MFMA16(a[mi], b[ni], acc[mi][ni]);
    }
    __syncthreads();   // all reads done before next stage overwrites
  }

  // epilogue: D layout col = lane&15, row = (lane>>4)*4 + reg  [m89/m91]
#pragma unroll
  for (int mi = 0; mi < 4; ++mi)
#pragma unroll
    for (int ni = 0; ni < 4; ++ni) {
      const int col = col0 + wc * 64 + ni * 16 + lrow;
#pragma unroll
      for (int j = 0; j < 4; ++j) {
        const int row = row0 + wr * 64 + mi * 16 + g * 4 + j;
        float v = acc[mi][ni][j];
        if (MODE == 0) {
          int bb = row >> 11, n = row & 2047;
          int sec = col / 384, c3 = col - sec * 384;
          int h = c3 >> 6, d = c3 & 63;
          u16 bv = f2bf(v);
          if (sec == 0)       qb [(((size_t)bb * HEADS + h) * NN + n) * 64 + d] = bv;
          else if (sec == 1)  kb [(((size_t)bb * HEADS + h) * NN + n) * 64 + d] = bv;
          else                vtb[(((size_t)bb * HEADS + h) * 64 + d) * NN + n] = bv;
        } else if (MODE == 1) {
          size_t idx = (size_t)row * N + col;
          v += res[idx];
          outF[idx] = v;
          outB[idx] = f2bf(v);
        } else if (MODE == 2) {
          v += bias[col];
          v = 0.5f * v * (1.0f + erff(v * 0.70710678118f));
          outB[(size_t)row * N + col] = f2bf(v);
        } else {
          size_t idx = (size_t)row * N + col;
          v += bias[col] + res[idx];
          outF[idx] = v;
          outB[idx] = f2bf(v);
        }
      }
    }
}

// ---------------- flash attention -------------------------------------------
// grid (N/64, B*HEADS); 4 waves x 16 q-rows; 32-key tiles, online softmax.
__global__ __launch_bounds__(256)
void attn_k(const u16* __restrict__ qb, const u16* __restrict__ kb,
            const u16* __restrict__ vtb, u16* __restrict__ ob) {
  __shared__ u16 plds[4][16 * 40];   // per-wave P tile, pad 40 (80B rows, 16B aligned)
  const int tid = threadIdx.x;
  const int lane = tid & 63, wv = tid >> 6;
  const int lrow = lane & 15, g = lane >> 4;
  const int bh = blockIdx.y;
  const int b = bh / HEADS, h = bh - b * HEADS;
  const int q0 = blockIdx.x * 64 + wv * 16;

  const u16* Qb = qb + ((size_t)bh * NN + q0) * 64;
  bf16x8 qf0 = *(const bf16x8*)(Qb + (size_t)lrow * 64 + g * 8);
  bf16x8 qf1 = *(const bf16x8*)(Qb + (size_t)lrow * 64 + 32 + g * 8);

  float m[4], s[4];
  f32x4 acc[4];
#pragma unroll
  for (int j = 0; j < 4; ++j) { m[j] = -1e30f; s[j] = 0.f; acc[j] = f32x4{0.f,0.f,0.f,0.f}; }
  const float scale = 0.125f;
  u16* myp = &plds[wv][0];

  for (int kt = 0; kt < NN / 32; ++kt) {
    const u16* Kb = kb + ((size_t)bh * NN + kt * 32) * 64;
    f32x4 st[2];
    st[0] = f32x4{0.f,0.f,0.f,0.f};
    st[1] = f32x4{0.f,0.f,0.f,0.f};
#pragma unroll
    for (int ct = 0; ct < 2; ++ct) {
      const u16* kr = Kb + (size_t)(ct * 16 + lrow) * 64 + g * 8;
      bf16x8 kf0 = *(const bf16x8*)(kr);
      bf16x8 kf1 = *(const bf16x8*)(kr + 32);
      st[ct] = MFMA16(qf0, kf0, st[ct]);
      st[ct] = MFMA16(qf1, kf1, st[ct]);
    }
    float p0[4], p1[4], al[4];
#pragma unroll
    for (int j = 0; j < 4; ++j) {
      float t = fmaxf(st[0][j], st[1][j]) * scale;
      t = fmaxf(t, __shfl_xor(t, 1));
      t = fmaxf(t, __shfl_xor(t, 2));
      t = fmaxf(t, __shfl_xor(t, 4));
      t = fmaxf(t, __shfl_xor(t, 8));
      float mn = fmaxf(m[j], t);
      al[j] = __expf(m[j] - mn);
      p0[j] = __expf(st[0][j] * scale - mn);
      p1[j] = __expf(st[1][j] * scale - mn);
      float r = p0[j] + p1[j];
      r += __shfl_xor(r, 1);
      r += __shfl_xor(r, 2);
      r += __shfl_xor(r, 4);
      r += __shfl_xor(r, 8);
      s[j] = s[j] * al[j] + r;
      m[j] = mn;
    }
#pragma unroll
    for (int dt = 0; dt < 4; ++dt) {
      f32x4 t = acc[dt];
      t[0] *= al[0]; t[1] *= al[1]; t[2] *= al[2]; t[3] *= al[3];
      acc[dt] = t;
    }
    __syncthreads();   // prior P reads complete before overwrite
#pragma unroll
    for (int j = 0; j < 4; ++j) {
      myp[(g * 4 + j) * 40 + lrow]      = f2bf(p0[j]);
      myp[(g * 4 + j) * 40 + 16 + lrow] = f2bf(p1[j]);
    }
    __syncthreads();   // P visible
    bf16x8 pa = *(const bf16x8*)(myp + lrow * 40 + g * 8);
#pragma unroll
    for (int dt = 0; dt < 4; ++dt) {
      const u16* vr = vtb + ((size_t)bh * 64 + dt * 16 + lrow) * NN + kt * 32 + g * 8;
      bf16x8 vf = *(const bf16x8*)vr;
      acc[dt] = MFMA16(pa, vf, acc[dt]);
    }
  }
#pragma unroll
  for (int dt = 0; dt < 4; ++dt)
#pragma unroll
    for (int j = 0; j < 4; ++j) {
      int qr = q0 + g * 4 + j;
      float v = acc[dt][j] / s[j];
      ob[((size_t)b * NN + qr) * 384 + h * 64 + dt * 16 + lrow] = f2bf(v);
    }
}

// ---------------------------------------------------------------------------
extern "C" void kernel_launch(void* const* d_in, const int* in_sizes, int n_in,
                              void* d_out, int out_size, void* d_ws, size_t ws_size,
                              hipStream_t stream) {
  (void)in_sizes; (void)n_in; (void)out_size; (void)ws_size;
  const float* x    = (const float*)d_in[0];
  const float* Wqkv = (const float*)d_in[1];
  const float* Wout = (const float*)d_in[2];
  const float* W1   = (const float*)d_in[3];
  const float* b1   = (const float*)d_in[4];
  const float* W2   = (const float*)d_in[5];
  const float* b2   = (const float*)d_in[6];
  float* out = (float*)d_out;

  char* ws = (char*)d_ws;
  size_t off = 0;
  auto alloc = [&](size_t bytes) { char* p = ws + off; off += (bytes + 255) & ~(size_t)255; return p; };
  u16*   wqkvT = (u16*)alloc((size_t)DEPTH * 1152 * 384 * 2);
  u16*   woutT = (u16*)alloc((size_t)DEPTH * 384 * 384 * 2);
  u16*   w1T   = (u16*)alloc((size_t)DEPTH * 1536 * 384 * 2);
  u16*   w2T   = (u16*)alloc((size_t)DEPTH * 384 * 1536 * 2);
  u16*   xbf   = (u16*)alloc((size_t)MTOT * 384 * 2);
  float* xres  = (float*)alloc((size_t)MTOT * 384 * 4);
  u16*   qbuf  = (u16*)alloc((size_t)MTOT * 384 * 2);
  u16*   kbuf  = (u16*)alloc((size_t)MTOT * 384 * 2);
  u16*   vtbuf = (u16*)alloc((size_t)MTOT * 384 * 2);
  u16*   obuf  = (u16*)alloc((size_t)MTOT * 384 * 2);
  u16*   hbuf  = (u16*)alloc((size_t)MTOT * 1536 * 2);

  wtrans_k<<<dim3(1152/32, 384/32, DEPTH), 256, 0, stream>>>(Wqkv, wqkvT, 384, 1152);
  wtrans_k<<<dim3( 384/32, 384/32, DEPTH), 256, 0, stream>>>(Wout, woutT, 384, 384);
  wtrans_k<<<dim3(1536/32, 384/32, DEPTH), 256, 0, stream>>>(W1,   w1T,   384, 1536);
  wtrans_k<<<dim3( 384/32,1536/32, DEPTH), 256, 0, stream>>>(W2,   w2T,   1536, 384);
  xprep_k<<<(MTOT*384 + 255)/256, 256, 0, stream>>>(x, xbf, MTOT*384);

  for (int l = 0; l < DEPTH; ++l) {
    gemm_k<0><<<dim3(1152/128, MTOT/128), 256, 0, stream>>>(
        xbf, wqkvT + (size_t)l*1152*384, nullptr, nullptr, nullptr, nullptr,
        qbuf, kbuf, vtbuf, MTOT, 1152, 384);
    attn_k<<<dim3(NN/64, BB*HEADS), 256, 0, stream>>>(qbuf, kbuf, vtbuf, obuf);
    gemm_k<1><<<dim3(384/128, MTOT/128), 256, 0, stream>>>(
        obuf, woutT + (size_t)l*384*384, nullptr, (l == 0 ? x : xres), xres, xbf,
        nullptr, nullptr, nullptr, MTOT, 384, 384);
    gemm_k<2><<<dim3(1536/128, MTOT/128), 256, 0, stream>>>(
        xbf, w1T + (size_t)l*1536*384, b1 + l*1536, nullptr, nullptr, hbuf,
        nullptr, nullptr, nullptr, MTOT, 1536, 384);
    gemm_k<3><<<dim3(384/128, MTOT/128), 256, 0, stream>>>(
        hbuf, w2T + (size_t)l*384*1536, b2 + l*384, xres,
        (l == DEPTH-1 ? out : xres), xbf,
        nullptr, nullptr, nullptr, MTOT, 384, 1536);
  }
}

// Round 2
// 1131.002 us; speedup vs baseline: 1.0017x; 1.0017x over previous
//
#include <hip/hip_runtime.h>
#include <stdint.h>

#define HEADS 6
#define NN 2048
#define BB 4
#define MTOT (BB*NN)   // 8192 rows
#define DEPTH 4

typedef unsigned short u16;
typedef __attribute__((ext_vector_type(8))) short bf16x8;
typedef __attribute__((ext_vector_type(4))) float f32x4;

#define MFMA16(a,b,c) __builtin_amdgcn_mfma_f32_16x16x32_bf16((a),(b),(c),0,0,0)

__device__ __forceinline__ u16 f2bf(float f) {
  union { float f; uint32_t u; } v; v.f = f;
  uint32_t r = v.u + 0x7fffu + ((v.u >> 16) & 1u);
  return (u16)(r >> 16);
}

__device__ __forceinline__ uint32_t pk2(float lo, float hi) {
  uint32_t r;
  asm("v_cvt_pk_bf16_f32 %0, %1, %2" : "=v"(r) : "v"(lo), "v"(hi));
  return r;
}

__device__ __forceinline__ void gload_lds16(const void* g, void* l) {
  __builtin_amdgcn_global_load_lds((const __attribute__((address_space(1))) void*)g,
                                   (__attribute__((address_space(3))) void*)l, 16, 0, 0);
}

// ---------------- weight transpose+convert: in[K][N] f32 -> out[N][K] bf16 ----
__global__ __launch_bounds__(256)
void wtrans_k(const float* __restrict__ in, u16* __restrict__ out, int K, int N) {
  __shared__ float t[32][33];
  const int z = blockIdx.z;
  in  += (size_t)z * K * N;
  out += (size_t)z * K * N;
  const int n0 = blockIdx.x * 32, k0 = blockIdx.y * 32;
  const int tx = threadIdx.x & 31, ty = threadIdx.x >> 5;   // 32 x 8
#pragma unroll
  for (int i = 0; i < 4; ++i)
    t[ty + i*8][tx] = in[(size_t)(k0 + ty + i*8) * N + n0 + tx];
  __syncthreads();
#pragma unroll
  for (int i = 0; i < 4; ++i)
    out[(size_t)(n0 + ty + i*8) * K + k0 + tx] = f2bf(t[tx][ty + i*8]);
}

// ---------------- x f32 -> bf16 --------------------------------------------
__global__ __launch_bounds__(256)
void xprep_k(const float* __restrict__ x, u16* __restrict__ xbf, int n) {
  int i = blockIdx.x * 256 + threadIdx.x;
  if (i < n) xbf[i] = f2bf(x[i]);
}

// ---------------- GEMM: C[M,N] = A[M,K](bf16) @ Bt[N,K]^T(bf16) -------------
template<int MODE>
__global__ __launch_bounds__(256)
void gemm_k(const u16* __restrict__ A, const u16* __restrict__ Bt,
            const float* __restrict__ bias, const float* __restrict__ res,
            float* __restrict__ outF, u16* __restrict__ outB,
            u16* __restrict__ qb, u16* __restrict__ kb, u16* __restrict__ vtb,
            int M, int N, int K) {
  __shared__ u16 smA[128 * 64];
  __shared__ u16 smB[128 * 64];
  const int tid = threadIdx.x;
  const int lane = tid & 63, wv = tid >> 6;
  const int wr = wv >> 1, wc = wv & 1;
  const int row0 = blockIdx.y * 128, col0 = blockIdx.x * 128;
  const int lrow = lane & 15, g = lane >> 4;

  f32x4 acc[4][4];
#pragma unroll
  for (int i = 0; i < 4; ++i)
#pragma unroll
    for (int j = 0; j < 4; ++j) acc[i][j] = f32x4{0.f, 0.f, 0.f, 0.f};

  const int ksteps = K >> 6;
  for (int kt = 0; kt < ksteps; ++kt) {
    const int k0 = kt << 6;
    const u16* Ab = A  + (size_t)row0 * K + k0;
    const u16* Bb = Bt + (size_t)col0 * K + k0;
#pragma unroll
    for (int r = 0; r < 4; ++r) {
      int c  = (r * 4 + wv) * 64 + lane;           // chunk 0..1023 (16B each)
      int rw = c >> 3;                              // tile row 0..127
      int kk = ((c & 7) ^ (rw & 7)) * 8;            // swizzled k-slot
      gload_lds16(Ab + (size_t)rw * K + kk, smA + (r * 4 + wv) * 512);
      gload_lds16(Bb + (size_t)rw * K + kk, smB + (r * 4 + wv) * 512);
    }
    __syncthreads();
#pragma unroll
    for (int kc = 0; kc < 2; ++kc) {
      bf16x8 a[4], b[4];
#pragma unroll
      for (int mi = 0; mi < 4; ++mi) {
        int r = wr * 64 + mi * 16 + lrow;
        int slot = (kc * 4 + g) ^ (r & 7);
        a[mi] = *(const bf16x8*)(smA + r * 64 + slot * 8);
      }
#pragma unroll
      for (int ni = 0; ni < 4; ++ni) {
        int r = wc * 64 + ni * 16 + lrow;
        int slot = (kc * 4 + g) ^ (r & 7);
        b[ni] = *(const bf16x8*)(smB + r * 64 + slot * 8);
      }
#pragma unroll
      for (int mi = 0; mi < 4; ++mi)
#pragma unroll
        for (int ni = 0; ni < 4; ++ni)
          acc[mi][ni] = MFMA16(a[mi], b[ni], acc[mi][ni]);
    }
    __syncthreads();
  }

#pragma unroll
  for (int mi = 0; mi < 4; ++mi)
#pragma unroll
    for (int ni = 0; ni < 4; ++ni) {
      const int col = col0 + wc * 64 + ni * 16 + lrow;
#pragma unroll
      for (int j = 0; j < 4; ++j) {
        const int row = row0 + wr * 64 + mi * 16 + g * 4 + j;
        float v = acc[mi][ni][j];
        if (MODE == 0) {
          int bb = row >> 11, n = row & 2047;
          int sec = col / 384, c3 = col - sec * 384;
          int h = c3 >> 6, d = c3 & 63;
          u16 bv = f2bf(v);
          if (sec == 0)       qb [(((size_t)bb * HEADS + h) * NN + n) * 64 + d] = bv;
          else if (sec == 1)  kb [(((size_t)bb * HEADS + h) * NN + n) * 64 + d] = bv;
          else                vtb[(((size_t)bb * HEADS + h) * 64 + d) * NN + n] = bv;
        } else if (MODE == 1) {
          size_t idx = (size_t)row * N + col;
          v += res[idx];
          outF[idx] = v;
          outB[idx] = f2bf(v);
        } else if (MODE == 2) {
          v += bias[col];
          v = 0.5f * v * (1.0f + erff(v * 0.70710678118f));
          outB[(size_t)row * N + col] = f2bf(v);
        } else {
          size_t idx = (size_t)row * N + col;
          v += bias[col] + res[idx];
          outF[idx] = v;
          outB[idx] = f2bf(v);
        }
      }
    }
}

// ---------------- flash attention, swapped-operand, 1 wave / 16 q-rows ------
// S^T = mfma(K,Q): col=lane&15=q, row=key.  O^T = mfma(V^T,P): col=q, row=d.
// All softmax state (m,s) is per-lane scalar; P round-trips a private LDS
// tile (no barriers anywhere: DS ops are in-order within a wave).
__global__ __launch_bounds__(64)
void attn_k(const u16* __restrict__ qb, const u16* __restrict__ kb,
            const u16* __restrict__ vtb, u16* __restrict__ ob) {
  __shared__ u16 plds[16 * 72];   // 16 q-rows x (64 keys + 8 pad)
  const int lane = threadIdx.x & 63;
  const int lrow = lane & 15, g = lane >> 4;
  const int bh = blockIdx.y;
  const int b = bh / HEADS, h = bh - b * HEADS;
  const int q0 = blockIdx.x * 16;

  const u16* Qb = qb + ((size_t)bh * NN + q0) * 64;
  // B-frag of Q: lane (q=lrow, g) holds Q[q][g*8+e]
  bf16x8 qf0 = *(const bf16x8*)(Qb + (size_t)lrow * 64 + g * 8);
  bf16x8 qf1 = *(const bf16x8*)(Qb + (size_t)lrow * 64 + 32 + g * 8);

  float m = -1e30f, s = 0.f;
  f32x4 acc[4];
#pragma unroll
  for (int j = 0; j < 4; ++j) acc[j] = f32x4{0.f, 0.f, 0.f, 0.f};
  const float sc2 = 0.125f * 1.44269504088896f;   // scale * log2(e)
  const f32x4 zero4 = {0.f, 0.f, 0.f, 0.f};

  const u16* Vbase = vtb + ((size_t)bh * 64 + lrow) * NN + g * 8;

  for (int kt = 0; kt < NN / 64; ++kt) {
    const u16* Kb = kb + ((size_t)bh * NN + kt * 64) * 64;
    f32x4 st[4];
#pragma unroll
    for (int ct = 0; ct < 4; ++ct) {
      const u16* kr = Kb + (size_t)(ct * 16 + lrow) * 64 + g * 8;
      bf16x8 kf0 = *(const bf16x8*)(kr);
      bf16x8 kf1 = *(const bf16x8*)(kr + 32);
      st[ct] = MFMA16(kf0, qf0, zero4);
      st[ct] = MFMA16(kf1, qf1, st[ct]);
    }
    // scores in log2 domain; local max over 16, then cross-g (2 shuffles)
    float z[16];
    float tmax = -1e30f;
#pragma unroll
    for (int ct = 0; ct < 4; ++ct)
#pragma unroll
      for (int j = 0; j < 4; ++j) {
        float t = st[ct][j] * sc2;
        z[ct * 4 + j] = t;
        tmax = fmaxf(tmax, t);
      }
    tmax = fmaxf(tmax, __shfl_xor(tmax, 16));
    tmax = fmaxf(tmax, __shfl_xor(tmax, 32));
    const bool grow = !__all(tmax <= m);
    const float mn = grow ? fmaxf(m, tmax) : m;
    float p[16];
#pragma unroll
    for (int i = 0; i < 16; ++i) p[i] = __builtin_amdgcn_exp2f(z[i] - mn);
    float r = ((p[0] + p[1]) + (p[2] + p[3])) + ((p[4] + p[5]) + (p[6] + p[7]))
            + ((p[8] + p[9]) + (p[10] + p[11])) + ((p[12] + p[13]) + (p[14] + p[15]));
    r += __shfl_xor(r, 16);
    r += __shfl_xor(r, 32);
    if (grow) {
      const float al = __builtin_amdgcn_exp2f(m - mn);
      s = s * al + r;
      m = mn;
#pragma unroll
      for (int dt = 0; dt < 4; ++dt) {
        f32x4 t = acc[dt];
        t[0] *= al; t[1] *= al; t[2] *= al; t[3] *= al;
        acc[dt] = t;
      }
    } else {
      s += r;
    }
    // P^T acc layout -> P[q][key] in LDS (keys ct*16+g*4+{0..3} per lane)
#pragma unroll
    for (int ct = 0; ct < 4; ++ct) {
      uint2 w;
      w.x = pk2(p[ct * 4 + 0], p[ct * 4 + 1]);
      w.y = pk2(p[ct * 4 + 2], p[ct * 4 + 3]);
      *(uint2*)(plds + lrow * 72 + ct * 16 + g * 4) = w;
    }
    // read back as B-frag of P: lane (q=lrow, g) reads P[q][kc*32 + g*8 ..]
    bf16x8 pa0 = *(const bf16x8*)(plds + lrow * 72 + g * 8);
    bf16x8 pa1 = *(const bf16x8*)(plds + lrow * 72 + 32 + g * 8);
    const u16* Vb = Vbase + kt * 64;
#pragma unroll
    for (int dt = 0; dt < 4; ++dt) {
      bf16x8 vf0 = *(const bf16x8*)(Vb + (size_t)dt * 16 * NN);
      bf16x8 vf1 = *(const bf16x8*)(Vb + (size_t)dt * 16 * NN + 32);
      acc[dt] = MFMA16(vf0, pa0, acc[dt]);
      acc[dt] = MFMA16(vf1, pa1, acc[dt]);
    }
  }
  const float inv = 1.f / s;
  u16* orow = ob + ((size_t)b * NN + q0 + lrow) * 384 + h * 64;
#pragma unroll
  for (int dt = 0; dt < 4; ++dt) {
    uint2 w;
    w.x = pk2(acc[dt][0] * inv, acc[dt][1] * inv);
    w.y = pk2(acc[dt][2] * inv, acc[dt][3] * inv);
    *(uint2*)(orow + dt * 16 + g * 4) = w;
  }
}

// ---------------------------------------------------------------------------
extern "C" void kernel_launch(void* const* d_in, const int* in_sizes, int n_in,
                              void* d_out, int out_size, void* d_ws, size_t ws_size,
                              hipStream_t stream) {
  (void)in_sizes; (void)n_in; (void)out_size; (void)ws_size;
  const float* x    = (const float*)d_in[0];
  const float* Wqkv = (const float*)d_in[1];
  const float* Wout = (const float*)d_in[2];
  const float* W1   = (const float*)d_in[3];
  const float* b1   = (const float*)d_in[4];
  const float* W2   = (const float*)d_in[5];
  const float* b2   = (const float*)d_in[6];
  float* out = (float*)d_out;

  char* ws = (char*)d_ws;
  size_t off = 0;
  auto alloc = [&](size_t bytes) { char* p = ws + off; off += (bytes + 255) & ~(size_t)255; return p; };
  u16*   wqkvT = (u16*)alloc((size_t)DEPTH * 1152 * 384 * 2);
  u16*   woutT = (u16*)alloc((size_t)DEPTH * 384 * 384 * 2);
  u16*   w1T   = (u16*)alloc((size_t)DEPTH * 1536 * 384 * 2);
  u16*   w2T   = (u16*)alloc((size_t)DEPTH * 384 * 1536 * 2);
  u16*   xbf   = (u16*)alloc((size_t)MTOT * 384 * 2);
  float* xres  = (float*)alloc((size_t)MTOT * 384 * 4);
  u16*   qbuf  = (u16*)alloc((size_t)MTOT * 384 * 2);
  u16*   kbuf  = (u16*)alloc((size_t)MTOT * 384 * 2);
  u16*   vtbuf = (u16*)alloc((size_t)MTOT * 384 * 2);
  u16*   obuf  = (u16*)alloc((size_t)MTOT * 384 * 2);
  u16*   hbuf  = (u16*)alloc((size_t)MTOT * 1536 * 2);

  wtrans_k<<<dim3(1152/32, 384/32, DEPTH), 256, 0, stream>>>(Wqkv, wqkvT, 384, 1152);
  wtrans_k<<<dim3( 384/32, 384/32, DEPTH), 256, 0, stream>>>(Wout, woutT, 384, 384);
  wtrans_k<<<dim3(1536/32, 384/32, DEPTH), 256, 0, stream>>>(W1,   w1T,   384, 1536);
  wtrans_k<<<dim3( 384/32,1536/32, DEPTH), 256, 0, stream>>>(W2,   w2T,   1536, 384);
  xprep_k<<<(MTOT*384 + 255)/256, 256, 0, stream>>>(x, xbf, MTOT*384);

  for (int l = 0; l < DEPTH; ++l) {
    gemm_k<0><<<dim3(1152/128, MTOT/128), 256, 0, stream>>>(
        xbf, wqkvT + (size_t)l*1152*384, nullptr, nullptr, nullptr, nullptr,
        qbuf, kbuf, vtbuf, MTOT, 1152, 384);
    attn_k<<<dim3(NN/16, BB*HEADS), 64, 0, stream>>>(qbuf, kbuf, vtbuf, obuf);
    gemm_k<1><<<dim3(384/128, MTOT/128), 256, 0, stream>>>(
        obuf, woutT + (size_t)l*384*384, nullptr, (l == 0 ? x : xres), xres, xbf,
        nullptr, nullptr, nullptr, MTOT, 384, 384);
    gemm_k<2><<<dim3(1536/128, MTOT/128), 256, 0, stream>>>(
        xbf, w1T + (size_t)l*1536*384, b1 + l*1536, nullptr, nullptr, hbuf,
        nullptr, nullptr, nullptr, MTOT, 1536, 384);
    gemm_k<3><<<dim3(384/128, MTOT/128), 256, 0, stream>>>(
        hbuf, w2T + (size_t)l*384*1536, b2 + l*384, xres,
        (l == DEPTH-1 ? out : xres), xbf,
        nullptr, nullptr, nullptr, MTOT, 384, 1536);
  }
}

// Round 3
// 661.673 us; speedup vs baseline: 1.7123x; 1.7093x over previous
//
#include <hip/hip_runtime.h>
#include <stdint.h>

#define HEADS 6
#define NN 2048
#define BB 4
#define MTOT (BB*NN)   // 8192 rows
#define DEPTH 4

typedef unsigned short u16;
typedef __attribute__((ext_vector_type(8))) short bf16x8;
typedef __attribute__((ext_vector_type(4))) float f32x4;

#define MFMA16(a,b,c) __builtin_amdgcn_mfma_f32_16x16x32_bf16((a),(b),(c),0,0,0)

__device__ __forceinline__ u16 f2bf(float f) {
  union { float f; uint32_t u; } v; v.f = f;
  uint32_t r = v.u + 0x7fffu + ((v.u >> 16) & 1u);
  return (u16)(r >> 16);
}

__device__ __forceinline__ uint32_t pk2(float lo, float hi) {
  uint32_t r;
  asm("v_cvt_pk_bf16_f32 %0, %1, %2" : "=v"(r) : "v"(lo), "v"(hi));
  return r;
}

__device__ __forceinline__ void gload_lds16(const void* g, void* l) {
  __builtin_amdgcn_global_load_lds((const __attribute__((address_space(1))) void*)g,
                                   (__attribute__((address_space(3))) void*)l, 16, 0, 0);
}

// ---------------- weight transpose+convert: in[K][N] f32 -> out[N][K] bf16 ----
__global__ __launch_bounds__(256)
void wtrans_k(const float* __restrict__ in, u16* __restrict__ out, int K, int N) {
  __shared__ float t[32][33];
  const int z = blockIdx.z;
  in  += (size_t)z * K * N;
  out += (size_t)z * K * N;
  const int n0 = blockIdx.x * 32, k0 = blockIdx.y * 32;
  const int tx = threadIdx.x & 31, ty = threadIdx.x >> 5;   // 32 x 8
#pragma unroll
  for (int i = 0; i < 4; ++i)
    t[ty + i*8][tx] = in[(size_t)(k0 + ty + i*8) * N + n0 + tx];
  __syncthreads();
#pragma unroll
  for (int i = 0; i < 4; ++i)
    out[(size_t)(n0 + ty + i*8) * K + k0 + tx] = f2bf(t[tx][ty + i*8]);
}

// ---------------- x f32 -> bf16 --------------------------------------------
__global__ __launch_bounds__(256)
void xprep_k(const float* __restrict__ x, u16* __restrict__ xbf, int n) {
  int i = blockIdx.x * 256 + threadIdx.x;
  if (i < n) xbf[i] = f2bf(x[i]);
}

// ---------------- GEMM: C[M,N] = A[M,K](bf16) @ Bt[N,K]^T(bf16) -------------
template<int MODE>
__global__ __launch_bounds__(256)
void gemm_k(const u16* __restrict__ A, const u16* __restrict__ Bt,
            const float* __restrict__ bias, const float* __restrict__ res,
            float* __restrict__ outF, u16* __restrict__ outB,
            u16* __restrict__ qb, u16* __restrict__ kb, u16* __restrict__ vtb,
            int M, int N, int K) {
  __shared__ u16 smA[128 * 64];
  __shared__ u16 smB[128 * 64];
  const int tid = threadIdx.x;
  const int lane = tid & 63, wv = tid >> 6;
  const int wr = wv >> 1, wc = wv & 1;
  const int row0 = blockIdx.y * 128, col0 = blockIdx.x * 128;
  const int lrow = lane & 15, g = lane >> 4;

  f32x4 acc[4][4];
#pragma unroll
  for (int i = 0; i < 4; ++i)
#pragma unroll
    for (int j = 0; j < 4; ++j) acc[i][j] = f32x4{0.f, 0.f, 0.f, 0.f};

  const int ksteps = K >> 6;
  for (int kt = 0; kt < ksteps; ++kt) {
    const int k0 = kt << 6;
    const u16* Ab = A  + (size_t)row0 * K + k0;
    const u16* Bb = Bt + (size_t)col0 * K + k0;
#pragma unroll
    for (int r = 0; r < 4; ++r) {
      int c  = (r * 4 + wv) * 64 + lane;           // chunk 0..1023 (16B each)
      int rw = c >> 3;                              // tile row 0..127
      int kk = ((c & 7) ^ (rw & 7)) * 8;            // swizzled k-slot
      gload_lds16(Ab + (size_t)rw * K + kk, smA + (r * 4 + wv) * 512);
      gload_lds16(Bb + (size_t)rw * K + kk, smB + (r * 4 + wv) * 512);
    }
    __syncthreads();
#pragma unroll
    for (int kc = 0; kc < 2; ++kc) {
      bf16x8 a[4], b[4];
#pragma unroll
      for (int mi = 0; mi < 4; ++mi) {
        int r = wr * 64 + mi * 16 + lrow;
        int slot = (kc * 4 + g) ^ (r & 7);
        a[mi] = *(const bf16x8*)(smA + r * 64 + slot * 8);
      }
#pragma unroll
      for (int ni = 0; ni < 4; ++ni) {
        int r = wc * 64 + ni * 16 + lrow;
        int slot = (kc * 4 + g) ^ (r & 7);
        b[ni] = *(const bf16x8*)(smB + r * 64 + slot * 8);
      }
#pragma unroll
      for (int mi = 0; mi < 4; ++mi)
#pragma unroll
        for (int ni = 0; ni < 4; ++ni)
          acc[mi][ni] = MFMA16(a[mi], b[ni], acc[mi][ni]);
    }
    __syncthreads();
  }

#pragma unroll
  for (int mi = 0; mi < 4; ++mi)
#pragma unroll
    for (int ni = 0; ni < 4; ++ni) {
      const int col = col0 + wc * 64 + ni * 16 + lrow;
#pragma unroll
      for (int j = 0; j < 4; ++j) {
        const int row = row0 + wr * 64 + mi * 16 + g * 4 + j;
        float v = acc[mi][ni][j];
        if (MODE == 0) {
          int bb = row >> 11, n = row & 2047;
          int sec = col / 384, c3 = col - sec * 384;
          int h = c3 >> 6, d = c3 & 63;
          u16 bv = f2bf(v);
          if (sec == 0)       qb [(((size_t)bb * HEADS + h) * NN + n) * 64 + d] = bv;
          else if (sec == 1)  kb [(((size_t)bb * HEADS + h) * NN + n) * 64 + d] = bv;
          else                vtb[(((size_t)bb * HEADS + h) * 64 + d) * NN + n] = bv;
        } else if (MODE == 1) {
          size_t idx = (size_t)row * N + col;
          v += res[idx];
          outF[idx] = v;
          outB[idx] = f2bf(v);
        } else if (MODE == 2) {
          v += bias[col];
          v = 0.5f * v * (1.0f + erff(v * 0.70710678118f));
          outB[(size_t)row * N + col] = f2bf(v);
        } else {
          size_t idx = (size_t)row * N + col;
          v += bias[col] + res[idx];
          outF[idx] = v;
          outB[idx] = f2bf(v);
        }
      }
    }
}

// ---------------- flash attention v3: 8 waves share LDS-staged K/V ----------
// Block = 512 thr (8 waves), 128 q-rows. Per 64-key tile: K (8KB) + V^T (8KB)
// double-buffered in LDS via global_load_lds (XOR-swizzled source, rule #21).
// Per-wave swapped-operand softmax: S^T = mfma(K,Q) -> col=q=lane&15.
__global__ __launch_bounds__(512)
void attn_k(const u16* __restrict__ qb, const u16* __restrict__ kb,
            const u16* __restrict__ vtb, u16* __restrict__ ob) {
  __shared__ u16 kbufs[2][64 * 64];
  __shared__ u16 vbufs[2][64 * 64];
  __shared__ u16 plds[8][16 * 72];
  const int tid = threadIdx.x;
  const int lane = tid & 63, wv = tid >> 6;
  const int lrow = lane & 15, g = lane >> 4;

  // bijective XCD swizzle: 384 blocks = 8 xcd * (3 bh * 16 qblk)
  const int lid = blockIdx.y * gridDim.x + blockIdx.x;
  const int xcd = lid & 7, ii = lid >> 3;
  const int bh = 3 * xcd + (ii >> 4);
  const int qblk = ii & 15;
  const int b = bh / HEADS, h = bh - b * HEADS;
  const int q0 = qblk * 128 + wv * 16;

  const u16* Qb = qb + ((size_t)bh * NN + q0) * 64;
  bf16x8 qf0 = *(const bf16x8*)(Qb + (size_t)lrow * 64 + g * 8);
  bf16x8 qf1 = *(const bf16x8*)(Qb + (size_t)lrow * 64 + 32 + g * 8);

  float m = -1e30f, s = 0.f;
  f32x4 acc[4];
#pragma unroll
  for (int j = 0; j < 4; ++j) acc[j] = f32x4{0.f, 0.f, 0.f, 0.f};
  const float sc2 = 0.125f * 1.44269504088896f;   // scale * log2(e)
  const f32x4 zero4 = {0.f, 0.f, 0.f, 0.f};

  const u16* Kb0 = kb  + (size_t)bh * NN * 64;
  const u16* Vt0 = vtb + (size_t)bh * 64 * NN;
  // this lane's staging chunk: c = wv*64+lane over 512 chunks of 16B
  const int sc_c = wv * 64 + lane;
  const int sc_r = sc_c >> 3;
  const int sc_s = (sc_c & 7) ^ (sc_r & 7);        // swizzled k-slot

  u16* myp = &plds[wv][0];
  const int NT = NN / 64;
  int cur = 0;

  // prologue: stage tile 0
  gload_lds16(Kb0 + (size_t)sc_r * 64 + sc_s * 8, kbufs[0] + wv * 512);
  gload_lds16(Vt0 + (size_t)sc_r * NN + sc_s * 8, vbufs[0] + wv * 512);
  __syncthreads();

  for (int kt = 0; kt < NT; ++kt) {
    if (kt + 1 < NT) {   // prefetch next tile into other buffer
      gload_lds16(Kb0 + (size_t)(kt + 1) * 64 * 64 + (size_t)sc_r * 64 + sc_s * 8,
                  kbufs[cur ^ 1] + wv * 512);
      gload_lds16(Vt0 + (size_t)sc_r * NN + (kt + 1) * 64 + sc_s * 8,
                  vbufs[cur ^ 1] + wv * 512);
    }
    const u16* kcur = kbufs[cur];
    const u16* vcur = vbufs[cur];
    f32x4 st[4];
#pragma unroll
    for (int ct = 0; ct < 4; ++ct) {
      const int r = ct * 16 + lrow;
      const u16* krow = kcur + r * 64;
      bf16x8 kf0 = *(const bf16x8*)(krow + ((g ^ (r & 7)) * 8));
      bf16x8 kf1 = *(const bf16x8*)(krow + (((4 + g) ^ (r & 7)) * 8));
      st[ct] = MFMA16(kf0, qf0, zero4);
      st[ct] = MFMA16(kf1, qf1, st[ct]);
    }
    float z[16];
    float tmax = -1e30f;
#pragma unroll
    for (int ct = 0; ct < 4; ++ct)
#pragma unroll
      for (int j = 0; j < 4; ++j) {
        float t = st[ct][j] * sc2;
        z[ct * 4 + j] = t;
        tmax = fmaxf(tmax, t);
      }
    tmax = fmaxf(tmax, __shfl_xor(tmax, 16));
    tmax = fmaxf(tmax, __shfl_xor(tmax, 32));
    const bool grow = !__all(tmax <= m);
    const float mn = grow ? fmaxf(m, tmax) : m;
    float p[16];
#pragma unroll
    for (int i = 0; i < 16; ++i) p[i] = __builtin_amdgcn_exp2f(z[i] - mn);
    float r = ((p[0] + p[1]) + (p[2] + p[3])) + ((p[4] + p[5]) + (p[6] + p[7]))
            + ((p[8] + p[9]) + (p[10] + p[11])) + ((p[12] + p[13]) + (p[14] + p[15]));
    r += __shfl_xor(r, 16);
    r += __shfl_xor(r, 32);
    if (grow) {
      const float al = __builtin_amdgcn_exp2f(m - mn);
      s = s * al + r;
      m = mn;
#pragma unroll
      for (int dt = 0; dt < 4; ++dt) {
        f32x4 t = acc[dt];
        t[0] *= al; t[1] *= al; t[2] *= al; t[3] *= al;
        acc[dt] = t;
      }
    } else {
      s += r;
    }
    // P^T acc layout -> P[q][key] in wave-private LDS (in-wave ordered, no bar)
#pragma unroll
    for (int ct = 0; ct < 4; ++ct) {
      uint2 w;
      w.x = pk2(p[ct * 4 + 0], p[ct * 4 + 1]);
      w.y = pk2(p[ct * 4 + 2], p[ct * 4 + 3]);
      *(uint2*)(myp + lrow * 72 + ct * 16 + g * 4) = w;
    }
    bf16x8 pa0 = *(const bf16x8*)(myp + lrow * 72 + g * 8);
    bf16x8 pa1 = *(const bf16x8*)(myp + lrow * 72 + 32 + g * 8);
#pragma unroll
    for (int dt = 0; dt < 4; ++dt) {
      const int r2 = dt * 16 + lrow;
      const u16* vrow = vcur + r2 * 64;
      bf16x8 vf0 = *(const bf16x8*)(vrow + ((g ^ (r2 & 7)) * 8));
      bf16x8 vf1 = *(const bf16x8*)(vrow + (((4 + g) ^ (r2 & 7)) * 8));
      acc[dt] = MFMA16(vf0, pa0, acc[dt]);
      acc[dt] = MFMA16(vf1, pa1, acc[dt]);
    }
    __syncthreads();   // drains vmcnt (prefetch done) + all reads of cur done
    cur ^= 1;
  }
  const float inv = 1.f / s;
  u16* orow = ob + ((size_t)b * NN + q0 + lrow) * 384 + h * 64;
#pragma unroll
  for (int dt = 0; dt < 4; ++dt) {
    uint2 w;
    w.x = pk2(acc[dt][0] * inv, acc[dt][1] * inv);
    w.y = pk2(acc[dt][2] * inv, acc[dt][3] * inv);
    *(uint2*)(orow + dt * 16 + g * 4) = w;
  }
}

// ---------------------------------------------------------------------------
extern "C" void kernel_launch(void* const* d_in, const int* in_sizes, int n_in,
                              void* d_out, int out_size, void* d_ws, size_t ws_size,
                              hipStream_t stream) {
  (void)in_sizes; (void)n_in; (void)out_size; (void)ws_size;
  const float* x    = (const float*)d_in[0];
  const float* Wqkv = (const float*)d_in[1];
  const float* Wout = (const float*)d_in[2];
  const float* W1   = (const float*)d_in[3];
  const float* b1   = (const float*)d_in[4];
  const float* W2   = (const float*)d_in[5];
  const float* b2   = (const float*)d_in[6];
  float* out = (float*)d_out;

  char* ws = (char*)d_ws;
  size_t off = 0;
  auto alloc = [&](size_t bytes) { char* p = ws + off; off += (bytes + 255) & ~(size_t)255; return p; };
  u16*   wqkvT = (u16*)alloc((size_t)DEPTH * 1152 * 384 * 2);
  u16*   woutT = (u16*)alloc((size_t)DEPTH * 384 * 384 * 2);
  u16*   w1T   = (u16*)alloc((size_t)DEPTH * 1536 * 384 * 2);
  u16*   w2T   = (u16*)alloc((size_t)DEPTH * 384 * 1536 * 2);
  u16*   xbf   = (u16*)alloc((size_t)MTOT * 384 * 2);
  float* xres  = (float*)alloc((size_t)MTOT * 384 * 4);
  u16*   qbuf  = (u16*)alloc((size_t)MTOT * 384 * 2);
  u16*   kbuf  = (u16*)alloc((size_t)MTOT * 384 * 2);
  u16*   vtbuf = (u16*)alloc((size_t)MTOT * 384 * 2);
  u16*   obuf  = (u16*)alloc((size_t)MTOT * 384 * 2);
  u16*   hbuf  = (u16*)alloc((size_t)MTOT * 1536 * 2);

  wtrans_k<<<dim3(1152/32, 384/32, DEPTH), 256, 0, stream>>>(Wqkv, wqkvT, 384, 1152);
  wtrans_k<<<dim3( 384/32, 384/32, DEPTH), 256, 0, stream>>>(Wout, woutT, 384, 384);
  wtrans_k<<<dim3(1536/32, 384/32, DEPTH), 256, 0, stream>>>(W1,   w1T,   384, 1536);
  wtrans_k<<<dim3( 384/32,1536/32, DEPTH), 256, 0, stream>>>(W2,   w2T,   1536, 384);
  xprep_k<<<(MTOT*384 + 255)/256, 256, 0, stream>>>(x, xbf, MTOT*384);

  for (int l = 0; l < DEPTH; ++l) {
    gemm_k<0><<<dim3(1152/128, MTOT/128), 256, 0, stream>>>(
        xbf, wqkvT + (size_t)l*1152*384, nullptr, nullptr, nullptr, nullptr,
        qbuf, kbuf, vtbuf, MTOT, 1152, 384);
    attn_k<<<dim3(16, 24), 512, 0, stream>>>(qbuf, kbuf, vtbuf, obuf);
    gemm_k<1><<<dim3(384/128, MTOT/128), 256, 0, stream>>>(
        obuf, woutT + (size_t)l*384*384, nullptr, (l == 0 ? x : xres), xres, xbf,
        nullptr, nullptr, nullptr, MTOT, 384, 384);
    gemm_k<2><<<dim3(1536/128, MTOT/128), 256, 0, stream>>>(
        xbf, w1T + (size_t)l*1536*384, b1 + l*1536, nullptr, nullptr, hbuf,
        nullptr, nullptr, nullptr, MTOT, 1536, 384);
    gemm_k<3><<<dim3(384/128, MTOT/128), 256, 0, stream>>>(
        hbuf, w2T + (size_t)l*384*1536, b2 + l*384, xres,
        (l == DEPTH-1 ? out : xres), xbf,
        nullptr, nullptr, nullptr, MTOT, 384, 1536);
  }
}

// Round 4
// 655.153 us; speedup vs baseline: 1.7293x; 1.0100x over previous
//
#include <hip/hip_runtime.h>
#include <stdint.h>

#define HEADS 6
#define NN 2048
#define BB 4
#define MTOT (BB*NN)   // 8192 rows
#define DEPTH 4

typedef unsigned short u16;
typedef __attribute__((ext_vector_type(8))) short bf16x8;
typedef __attribute__((ext_vector_type(4))) float f32x4;
typedef __attribute__((ext_vector_type(16))) float f32x16;

#define MFMA16(a,b,c) __builtin_amdgcn_mfma_f32_16x16x32_bf16((a),(b),(c),0,0,0)
#define MFMA32(a,b,c) __builtin_amdgcn_mfma_f32_32x32x16_bf16((a),(b),(c),0,0,0)

// scale * log2(e): fold softmax scaling into Q at QKV-epilogue time
#define QSC 0.18033688011112042f

__device__ __forceinline__ u16 f2bf(float f) {
  union { float f; uint32_t u; } v; v.f = f;
  uint32_t r = v.u + 0x7fffu + ((v.u >> 16) & 1u);
  return (u16)(r >> 16);
}

__device__ __forceinline__ uint32_t pk2(float lo, float hi) {
  uint32_t r;
  asm("v_cvt_pk_bf16_f32 %0, %1, %2" : "=v"(r) : "v"(lo), "v"(hi));
  return r;
}

__device__ __forceinline__ void gload_lds16(const void* g, void* l) {
  __builtin_amdgcn_global_load_lds((const __attribute__((address_space(1))) void*)g,
                                   (__attribute__((address_space(3))) void*)l, 16, 0, 0);
}

// ---------------- weight transpose+convert: in[K][N] f32 -> out[N][K] bf16 ----
__global__ __launch_bounds__(256)
void wtrans_k(const float* __restrict__ in, u16* __restrict__ out, int K, int N) {
  __shared__ float t[32][33];
  const int z = blockIdx.z;
  in  += (size_t)z * K * N;
  out += (size_t)z * K * N;
  const int n0 = blockIdx.x * 32, k0 = blockIdx.y * 32;
  const int tx = threadIdx.x & 31, ty = threadIdx.x >> 5;   // 32 x 8
#pragma unroll
  for (int i = 0; i < 4; ++i)
    t[ty + i*8][tx] = in[(size_t)(k0 + ty + i*8) * N + n0 + tx];
  __syncthreads();
#pragma unroll
  for (int i = 0; i < 4; ++i)
    out[(size_t)(n0 + ty + i*8) * K + k0 + tx] = f2bf(t[tx][ty + i*8]);
}

// ---------------- x f32 -> bf16 --------------------------------------------
__global__ __launch_bounds__(256)
void xprep_k(const float* __restrict__ x, u16* __restrict__ xbf, int n) {
  int i = blockIdx.x * 256 + threadIdx.x;
  if (i < n) xbf[i] = f2bf(x[i]);
}

// ---------------- GEMM: C[M,N] = A[M,K](bf16) @ Bt[N,K]^T(bf16) -------------
template<int MODE>
__global__ __launch_bounds__(256)
void gemm_k(const u16* __restrict__ A, const u16* __restrict__ Bt,
            const float* __restrict__ bias, const float* __restrict__ res,
            float* __restrict__ outF, u16* __restrict__ outB,
            u16* __restrict__ qb, u16* __restrict__ kb, u16* __restrict__ vtb,
            int M, int N, int K) {
  __shared__ u16 smA[128 * 64];
  __shared__ u16 smB[128 * 64];
  const int tid = threadIdx.x;
  const int lane = tid & 63, wv = tid >> 6;
  const int wr = wv >> 1, wc = wv & 1;
  const int row0 = blockIdx.y * 128, col0 = blockIdx.x * 128;
  const int lrow = lane & 15, g = lane >> 4;

  f32x4 acc[4][4];
#pragma unroll
  for (int i = 0; i < 4; ++i)
#pragma unroll
    for (int j = 0; j < 4; ++j) acc[i][j] = f32x4{0.f, 0.f, 0.f, 0.f};

  const int ksteps = K >> 6;
  for (int kt = 0; kt < ksteps; ++kt) {
    const int k0 = kt << 6;
    const u16* Ab = A  + (size_t)row0 * K + k0;
    const u16* Bb = Bt + (size_t)col0 * K + k0;
#pragma unroll
    for (int r = 0; r < 4; ++r) {
      int c  = (r * 4 + wv) * 64 + lane;           // chunk 0..1023 (16B each)
      int rw = c >> 3;                              // tile row 0..127
      int kk = ((c & 7) ^ (rw & 7)) * 8;            // swizzled k-slot
      gload_lds16(Ab + (size_t)rw * K + kk, smA + (r * 4 + wv) * 512);
      gload_lds16(Bb + (size_t)rw * K + kk, smB + (r * 4 + wv) * 512);
    }
    __syncthreads();
#pragma unroll
    for (int kc = 0; kc < 2; ++kc) {
      bf16x8 a[4], b[4];
#pragma unroll
      for (int mi = 0; mi < 4; ++mi) {
        int r = wr * 64 + mi * 16 + lrow;
        int slot = (kc * 4 + g) ^ (r & 7);
        a[mi] = *(const bf16x8*)(smA + r * 64 + slot * 8);
      }
#pragma unroll
      for (int ni = 0; ni < 4; ++ni) {
        int r = wc * 64 + ni * 16 + lrow;
        int slot = (kc * 4 + g) ^ (r & 7);
        b[ni] = *(const bf16x8*)(smB + r * 64 + slot * 8);
      }
#pragma unroll
      for (int mi = 0; mi < 4; ++mi)
#pragma unroll
        for (int ni = 0; ni < 4; ++ni)
          acc[mi][ni] = MFMA16(a[mi], b[ni], acc[mi][ni]);
    }
    __syncthreads();
  }

#pragma unroll
  for (int mi = 0; mi < 4; ++mi)
#pragma unroll
    for (int ni = 0; ni < 4; ++ni) {
      const int col = col0 + wc * 64 + ni * 16 + lrow;
#pragma unroll
      for (int j = 0; j < 4; ++j) {
        const int row = row0 + wr * 64 + mi * 16 + g * 4 + j;
        float v = acc[mi][ni][j];
        if (MODE == 0) {
          int bb = row >> 11, n = row & 2047;
          int sec = col / 384, c3 = col - sec * 384;
          int h = c3 >> 6, d = c3 & 63;
          if (sec == 0) {
            qb [(((size_t)bb * HEADS + h) * NN + n) * 64 + d] = f2bf(v * QSC);
          } else if (sec == 1) {
            kb [(((size_t)bb * HEADS + h) * NN + n) * 64 + d] = f2bf(v);
          } else {
            vtb[(((size_t)bb * HEADS + h) * 64 + d) * NN + n] = f2bf(v);
          }
        } else if (MODE == 1) {
          size_t idx = (size_t)row * N + col;
          v += res[idx];
          outF[idx] = v;
          outB[idx] = f2bf(v);
        } else if (MODE == 2) {
          v += bias[col];
          v = 0.5f * v * (1.0f + erff(v * 0.70710678118f));
          outB[(size_t)row * N + col] = f2bf(v);
        } else {
          size_t idx = (size_t)row * N + col;
          v += bias[col] + res[idx];
          outF[idx] = v;
          outB[idx] = f2bf(v);
        }
      }
    }
}

// ---------------- flash attention v4: 32x32 MFMA, 32 q-rows/wave ------------
// Block = 256 thr (4 waves), 128 q-rows. K/V 64-key tiles double-buffered in
// LDS. S^T = mfma32(K,Q): col=lane&31=q, row=key=(reg&3)+8*(reg>>2)+4*(lane>>5).
// P re-fragmented via per-wave swizzled LDS tile (write: C-layout; read and
// V-read use identical position map -> A/B k-map cancels). Q pre-scaled by
// 0.125*log2e so softmax runs in exp2 domain with no per-tile multiplies.
__global__ __launch_bounds__(256)
void attn_k(const u16* __restrict__ qb, const u16* __restrict__ kb,
            const u16* __restrict__ vtb, u16* __restrict__ ob) {
  __shared__ u16 kbufs[2][64 * 64];
  __shared__ u16 vbufs[2][64 * 64];
  __shared__ u16 plds[4][32 * 64];   // per wave: 32 q x 64 keys, XOR-swizzled slots
  const int tid = threadIdx.x;
  const int lane = tid & 63, wv = tid >> 6;
  const int l31 = lane & 31, h2 = lane >> 5;
  const int qx = l31 & 7;            // row-XOR for P swizzle

  // bijective XCD swizzle: 384 blocks = 8 xcd * (3 bh * 16 qblk)
  const int lid = blockIdx.y * gridDim.x + blockIdx.x;
  const int xcd = lid & 7, ii = lid >> 3;
  const int bh = 3 * xcd + (ii >> 4);
  const int qblk = ii & 15;
  const int b = bh / HEADS, h = bh - b * HEADS;
  const int q0 = qblk * 128 + wv * 32;

  // Q B-frags: lane (q=l31, h2) holds Q[q][pos ct2*16+8*h2+e]
  const u16* Qb = qb + ((size_t)bh * NN + q0 + l31) * 64;
  bf16x8 qf[4];
#pragma unroll
  for (int ct2 = 0; ct2 < 4; ++ct2)
    qf[ct2] = *(const bf16x8*)(Qb + ct2 * 16 + h2 * 8);

  float m = -1e30f, s = 0.f;
  f32x16 acc[2];
#pragma unroll
  for (int dg = 0; dg < 2; ++dg)
#pragma unroll
    for (int i = 0; i < 16; ++i) acc[dg][i] = 0.f;
  const f32x16 zero16 = {0.f,0.f,0.f,0.f,0.f,0.f,0.f,0.f,0.f,0.f,0.f,0.f,0.f,0.f,0.f,0.f};

  const u16* Kb0 = kb  + (size_t)bh * NN * 64;
  const u16* Vt0 = vtb + (size_t)bh * 64 * NN;
  // staging: 512 chunks of 16B per 8KB tile; 256 lanes -> 2 chunks each
  const int cA = wv * 64 + lane;
  const int rA = cA >> 3, sA = (cA & 7) ^ (rA & 7);
  const int cB = cA + 256;
  const int rB = cB >> 3, sB = (cB & 7) ^ (rB & 7);

  u16* myp = &plds[wv][0];
  const int NT = NN / 64;
  int cur = 0;

#define STAGE_KV(buf, t) do { \
    gload_lds16(Kb0 + (size_t)(t) * 4096 + (size_t)rA * 64 + sA * 8, kbufs[buf] + wv * 512); \
    gload_lds16(Kb0 + (size_t)(t) * 4096 + (size_t)rB * 64 + sB * 8, kbufs[buf] + 2048 + wv * 512); \
    gload_lds16(Vt0 + (size_t)rA * NN + (t) * 64 + sA * 8, vbufs[buf] + wv * 512); \
    gload_lds16(Vt0 + (size_t)rB * NN + (t) * 64 + sB * 8, vbufs[buf] + 2048 + wv * 512); \
  } while (0)

  STAGE_KV(0, 0);
  __syncthreads();

  for (int kt = 0; kt < NT; ++kt) {
    if (kt + 1 < NT) STAGE_KV(cur ^ 1, kt + 1);
    const u16* kcur = kbufs[cur];
    const u16* vcur = vbufs[cur];

    // S^T = K * Q over the 64-key tile: 2 key-groups x 4 d-steps
    f32x16 st[2];
#pragma unroll
    for (int kg = 0; kg < 2; ++kg) {
      f32x16 a = zero16;
      const u16* krow = kcur + (kg * 32 + l31) * 64;
#pragma unroll
      for (int ct2 = 0; ct2 < 4; ++ct2) {
        bf16x8 kf = *(const bf16x8*)(krow + ((ct2 * 2 + h2) ^ qx) * 8);
        a = MFMA32(kf, qf[ct2], a);
      }
      st[kg] = a;
    }

    // deferred-max online softmax (scores already in log2 domain)
    float tmax = -1e30f;
#pragma unroll
    for (int kg = 0; kg < 2; ++kg)
#pragma unroll
      for (int i = 0; i < 16; ++i) tmax = fmaxf(tmax, st[kg][i]);
    if (!__all(tmax <= m + 8.0f)) {
      float rm = fmaxf(tmax, __shfl_xor(tmax, 32));
      float mn = fmaxf(m, rm);
      float al = __builtin_amdgcn_exp2f(m - mn);
      s *= al;
#pragma unroll
      for (int dg = 0; dg < 2; ++dg)
#pragma unroll
        for (int i = 0; i < 16; ++i) acc[dg][i] *= al;
      m = mn;
    }
    float p[2][16];
    float r = 0.f;
#pragma unroll
    for (int kg = 0; kg < 2; ++kg)
#pragma unroll
      for (int i = 0; i < 16; ++i) {
        float t = __builtin_amdgcn_exp2f(st[kg][i] - m);
        p[kg][i] = t;
        r += t;
      }
    r += __shfl_xor(r, 32);
    s += r;

    // P -> wave-private LDS. write via C-layout: regs 4c..4c+3 = keys
    // kg*32 + 8c + 4*h2 + {0..3}; slot-swizzled by q&7.
#pragma unroll
    for (int kg = 0; kg < 2; ++kg)
#pragma unroll
      for (int c = 0; c < 4; ++c) {
        uint2 w;
        w.x = pk2(p[kg][4*c + 0], p[kg][4*c + 1]);
        w.y = pk2(p[kg][4*c + 2], p[kg][4*c + 3]);
        *(uint2*)(myp + l31 * 64 + (((kg * 4 + c) ^ qx) * 8) + h2 * 4) = w;
      }

    // PV: O^T += V^T * P.  A-slot and B-slot (h2,e) both carry key-position
    // kgp*16+8*h2+e -> HW k-map cancels.
#pragma unroll
    for (int kgp = 0; kgp < 4; ++kgp) {
      bf16x8 pf = *(const bf16x8*)(myp + l31 * 64 + (((kgp * 2 + h2) ^ qx) * 8));
#pragma unroll
      for (int dg = 0; dg < 2; ++dg) {
        const int d = dg * 32 + l31;
        bf16x8 vf = *(const bf16x8*)(vcur + d * 64 + (((kgp * 2 + h2) ^ (d & 7)) * 8));
        acc[dg] = MFMA32(vf, pf, acc[dg]);
      }
    }
    __syncthreads();   // prefetch landed + all reads of cur done
    cur ^= 1;
  }

  const float inv = 1.f / s;
  u16* orow = ob + ((size_t)b * NN + q0 + l31) * 384 + h * 64;
#pragma unroll
  for (int dg = 0; dg < 2; ++dg)
#pragma unroll
    for (int c = 0; c < 4; ++c) {
      uint2 w;
      w.x = pk2(acc[dg][4*c + 0] * inv, acc[dg][4*c + 1] * inv);
      w.y = pk2(acc[dg][4*c + 2] * inv, acc[dg][4*c + 3] * inv);
      *(uint2*)(orow + dg * 32 + 8 * c + 4 * h2) = w;
    }
}

// ---------------------------------------------------------------------------
extern "C" void kernel_launch(void* const* d_in, const int* in_sizes, int n_in,
                              void* d_out, int out_size, void* d_ws, size_t ws_size,
                              hipStream_t stream) {
  (void)in_sizes; (void)n_in; (void)out_size; (void)ws_size;
  const float* x    = (const float*)d_in[0];
  const float* Wqkv = (const float*)d_in[1];
  const float* Wout = (const float*)d_in[2];
  const float* W1   = (const float*)d_in[3];
  const float* b1   = (const float*)d_in[4];
  const float* W2   = (const float*)d_in[5];
  const float* b2   = (const float*)d_in[6];
  float* out = (float*)d_out;

  char* ws = (char*)d_ws;
  size_t off = 0;
  auto alloc = [&](size_t bytes) { char* p = ws + off; off += (bytes + 255) & ~(size_t)255; return p; };
  u16*   wqkvT = (u16*)alloc((size_t)DEPTH * 1152 * 384 * 2);
  u16*   woutT = (u16*)alloc((size_t)DEPTH * 384 * 384 * 2);
  u16*   w1T   = (u16*)alloc((size_t)DEPTH * 1536 * 384 * 2);
  u16*   w2T   = (u16*)alloc((size_t)DEPTH * 384 * 1536 * 2);
  u16*   xbf   = (u16*)alloc((size_t)MTOT * 384 * 2);
  float* xres  = (float*)alloc((size_t)MTOT * 384 * 4);
  u16*   qbuf  = (u16*)alloc((size_t)MTOT * 384 * 2);
  u16*   kbuf  = (u16*)alloc((size_t)MTOT * 384 * 2);
  u16*   vtbuf = (u16*)alloc((size_t)MTOT * 384 * 2);
  u16*   obuf  = (u16*)alloc((size_t)MTOT * 384 * 2);
  u16*   hbuf  = (u16*)alloc((size_t)MTOT * 1536 * 2);

  wtrans_k<<<dim3(1152/32, 384/32, DEPTH), 256, 0, stream>>>(Wqkv, wqkvT, 384, 1152);
  wtrans_k<<<dim3( 384/32, 384/32, DEPTH), 256, 0, stream>>>(Wout, woutT, 384, 384);
  wtrans_k<<<dim3(1536/32, 384/32, DEPTH), 256, 0, stream>>>(W1,   w1T,   384, 1536);
  wtrans_k<<<dim3( 384/32,1536/32, DEPTH), 256, 0, stream>>>(W2,   w2T,   1536, 384);
  xprep_k<<<(MTOT*384 + 255)/256, 256, 0, stream>>>(x, xbf, MTOT*384);

  for (int l = 0; l < DEPTH; ++l) {
    gemm_k<0><<<dim3(1152/128, MTOT/128), 256, 0, stream>>>(
        xbf, wqkvT + (size_t)l*1152*384, nullptr, nullptr, nullptr, nullptr,
        qbuf, kbuf, vtbuf, MTOT, 1152, 384);
    attn_k<<<dim3(16, 24), 256, 0, stream>>>(qbuf, kbuf, vtbuf, obuf);
    gemm_k<1><<<dim3(384/128, MTOT/128), 256, 0, stream>>>(
        obuf, woutT + (size_t)l*384*384, nullptr, (l == 0 ? x : xres), xres, xbf,
        nullptr, nullptr, nullptr, MTOT, 384, 384);
    gemm_k<2><<<dim3(1536/128, MTOT/128), 256, 0, stream>>>(
        xbf, w1T + (size_t)l*1536*384, b1 + l*1536, nullptr, nullptr, hbuf,
        nullptr, nullptr, nullptr, MTOT, 1536, 384);
    gemm_k<3><<<dim3(384/128, MTOT/128), 256, 0, stream>>>(
        hbuf, w2T + (size_t)l*384*1536, b2 + l*384, xres,
        (l == DEPTH-1 ? out : xres), xbf,
        nullptr, nullptr, nullptr, MTOT, 384, 1536);
  }
}